// Round 4
// baseline (1560.095 us; speedup 1.0000x reference)
//
#include <hip/hip_runtime.h>

typedef __attribute__((ext_vector_type(8))) short short8;
typedef __attribute__((ext_vector_type(4))) float f32x4;
typedef unsigned short ushort_t;
typedef unsigned int uint_t;

#define BB 4
#define T_ 1024
#define T2 2048
#define DD 256
#define DIN 512
#define NMARK 64
#define LNEPS 1e-5f
#define KDIV (-0.035977892078032f)

__device__ __forceinline__ ushort_t f2bf(float f) {
  unsigned int u = __float_as_uint(f);
  unsigned int r = (u + 0x7fffu + ((u >> 16) & 1u)) >> 16;
  return (ushort_t)r;
}
__device__ __forceinline__ uint_t pack2(float a, float b) {
  return (uint_t)f2bf(a) | ((uint_t)f2bf(b) << 16);
}

// ---------- init: type/time embeddings -> Xh (bf16), Cur = 0 ----------
__global__ __launch_bounds__(256) void k_init(const float* __restrict__ ev,
                                              const float* __restrict__ tm,
                                              const float* __restrict__ Wt,
                                              const float* __restrict__ bt,
                                              ushort_t* __restrict__ Xh,
                                              float* __restrict__ Cur) {
  const int btq = blockIdx.x;
  const int b = btq >> 10;
  const int t = btq & 1023;
  const int d = threadIdx.x;
  __shared__ float evs[NMARK];
  if (d < NMARK) evs[d] = ev[(size_t)btq * NMARK + d];
  __syncthreads();
  float s = bt[d];
#pragma unroll
  for (int m = 0; m < NMARK; ++m) s += evs[m] * Wt[m * DD + d];
  const float te_type = tanhf(s);
  const float tv = tm[btq];
  const int i = d >> 1;
  const float dv = expf((float)(2 * i) * KDIV);
  const float ang = tv * dv;
  const float te_time = (d & 1) ? cosf(ang) : sinf(ang);
  ushort_t* Xb = Xh + (size_t)b * T2 * DIN;
  const ushort_t tt = f2bf(te_time);
  Xb[(size_t)t * DIN + d] = f2bf(te_type);
  Xb[(size_t)t * DIN + DD + d] = tt;
  Xb[(size_t)(T_ + t) * DIN + d] = 0;
  Xb[(size_t)(T_ + t) * DIN + DD + d] = tt;
  Cur[((size_t)b * T_ + t) * DD + d] = 0.0f;
}

// ---------- weight transpose: W[hl][k][n] f32 -> WT[mat][n][k] bf16 ----------
__global__ __launch_bounds__(256) void k_transW(const float* __restrict__ Wq,
                                                const float* __restrict__ Wk,
                                                const float* __restrict__ Wv,
                                                ushort_t* __restrict__ WT) {
  const int mi = blockIdx.x;
  const int wsel = mi / 12, hl = mi % 12;
  const float* W = ((wsel == 0) ? Wq : (wsel == 1) ? Wk : Wv) + (size_t)hl * DIN * DD;
  const int t = blockIdx.y;
  const int k0 = (t >> 2) * 64, n0 = (t & 3) * 64;
  __shared__ float Ts[64][65];
  const int tid = threadIdx.x;
#pragma unroll
  for (int i = 0; i < 16; ++i) {
    const int idx = tid + i * 256;
    const int r = idx >> 6, c = idx & 63;
    Ts[r][c] = W[(size_t)(k0 + r) * DD + n0 + c];
  }
  __syncthreads();
  ushort_t* D = WT + (size_t)mi * DD * DIN;
#pragma unroll
  for (int i = 0; i < 16; ++i) {
    const int idx = tid + i * 256;
    const int rn = idx >> 6, ck = idx & 63;
    D[(size_t)(n0 + rn) * DIN + k0 + ck] = f2bf(Ts[ck][rn]);
  }
}

// ---------- QKV GEMM: [8192x512]x[512x256] via MFMA; z selects Q/K/V ----------
__global__ __launch_bounds__(256) void k_qkv(const ushort_t* __restrict__ Xh,
                                             const ushort_t* __restrict__ WT,
                                             const float* __restrict__ bq,
                                             const float* __restrict__ bk,
                                             const float* __restrict__ bv,
                                             ushort_t* __restrict__ Qh,
                                             ushort_t* __restrict__ Kh,
                                             ushort_t* __restrict__ VT,
                                             int hl) {
  const int m0 = blockIdx.x * 128;
  const int n0 = blockIdx.y * 128;
  const int wsel = blockIdx.z;
  const ushort_t* Bt = WT + ((size_t)(wsel * 12 + hl)) * DD * DIN + (size_t)n0 * DIN;
  const float* bias = (wsel == 0) ? bq : (wsel == 1) ? bk : bv;

  __shared__ ushort_t As[128 * 64];
  __shared__ ushort_t Bs[128 * 64];
  const int tid = threadIdx.x;
  const int w = tid >> 6, lane = tid & 63;
  const int wr = w >> 1, wc = w & 1;
  const int lr = lane & 15, kg = lane >> 4;

  f32x4 acc[4][4];
  const f32x4 z4 = {0.f, 0.f, 0.f, 0.f};
#pragma unroll
  for (int a = 0; a < 4; ++a)
#pragma unroll
    for (int c = 0; c < 4; ++c) acc[a][c] = z4;

  for (int k0 = 0; k0 < DIN; k0 += 64) {
#pragma unroll
    for (int i = 0; i < 4; ++i) {
      const int idx = tid + i * 256;
      const int row = idx >> 3, ch = idx & 7;
      const int db = row * 128 + ((ch * 16) ^ ((row & 7) << 4));
      uint4 va = *(const uint4*)&Xh[(size_t)(m0 + row) * DIN + k0 + ch * 8];
      *(uint4*)((char*)As + db) = va;
      uint4 vb = *(const uint4*)&Bt[(size_t)row * DIN + k0 + ch * 8];
      *(uint4*)((char*)Bs + db) = vb;
    }
    __syncthreads();
#pragma unroll
    for (int kk = 0; kk < 2; ++kk) {
      short8 af[4], bfr[4];
      const int cb = kk * 64 + kg * 16;
#pragma unroll
      for (int mi = 0; mi < 4; ++mi) {
        const int row = wr * 64 + mi * 16 + lr;
        af[mi] = *(const short8*)((const char*)As + row * 128 + (cb ^ ((row & 7) << 4)));
      }
#pragma unroll
      for (int ni = 0; ni < 4; ++ni) {
        const int row = wc * 64 + ni * 16 + lr;
        bfr[ni] = *(const short8*)((const char*)Bs + row * 128 + (cb ^ ((row & 7) << 4)));
      }
#pragma unroll
      for (int mi = 0; mi < 4; ++mi)
#pragma unroll
        for (int ni = 0; ni < 4; ++ni)
          acc[mi][ni] = __builtin_amdgcn_mfma_f32_16x16x32_bf16(af[mi], bfr[ni], acc[mi][ni], 0, 0, 0);
    }
    __syncthreads();
  }

  if (wsel < 2) {
    ushort_t* C = (wsel == 0) ? Qh : Kh;
#pragma unroll
    for (int mi = 0; mi < 4; ++mi)
#pragma unroll
      for (int ni = 0; ni < 4; ++ni) {
        const int col = n0 + wc * 64 + ni * 16 + lr;
        const float bcol = bias[col];
        const int rbase = m0 + wr * 64 + mi * 16 + kg * 4;
#pragma unroll
        for (int r = 0; r < 4; ++r)
          C[(size_t)(rbase + r) * DD + col] = f2bf(acc[mi][ni][r] + bcol);
      }
  } else {
    const int b = m0 >> 11;
    const int t0 = m0 & 2047;
#pragma unroll
    for (int mi = 0; mi < 4; ++mi)
#pragma unroll
      for (int ni = 0; ni < 4; ++ni) {
        const int col = n0 + wc * 64 + ni * 16 + lr;
        const float bcol = bias[col];
        const int tb = t0 + wr * 64 + mi * 16 + kg * 4;
        uint2 pk;
        pk.x = pack2(acc[mi][ni][0] + bcol, acc[mi][ni][1] + bcol);
        pk.y = pack2(acc[mi][ni][2] + bcol, acc[mi][ni][3] + bcol);
        *(uint2*)(VT + ((size_t)b * DD + col) * T2 + tb) = pk;
      }
  }
}

// ---------- fused flash attention: QK^T + online softmax + PV + epilogue ----------
// grid (72, BB): ii=0..63 -> q-chunks (heavy first); ii=64..71 -> row0 mean-V blocks.
// LDS map: Qs 0..16K, Ks 16K..48K, Vs 48K..80K, Sf 80K..88.5K, Ps ..92.6K, fac/linv.
__global__ __launch_bounds__(256) void k_flash(const ushort_t* __restrict__ Qh,
                                               const ushort_t* __restrict__ Kh,
                                               const ushort_t* __restrict__ VT,
                                               float* __restrict__ Cur,
                                               ushort_t* __restrict__ Xh,
                                               float* __restrict__ out,
                                               const float* __restrict__ nw,
                                               const float* __restrict__ nb,
                                               int lastLayer, int h) {
  __shared__ char lds[95232];
  const int tid = threadIdx.x;
  const int b = blockIdx.y;

  if (blockIdx.x >= 64) {
    // ----- row 0: O[b,0,:] = mean over all 2048 V rows -> Xh top row 0 -----
    const int c0 = ((int)blockIdx.x - 64) * 32;
    const int col = c0 + (tid & 31);
    const int chunk = tid >> 5;
    const ushort_t* vp = VT + ((size_t)b * DD + col) * T2 + chunk * 256;
    float s = 0.f;
#pragma unroll
    for (int j = 0; j < 256; j += 8) {
      uint4 v = *(const uint4*)(vp + j);
      const uint_t vs[4] = {v.x, v.y, v.z, v.w};
#pragma unroll
      for (int q = 0; q < 4; ++q) {
        s += __uint_as_float(vs[q] << 16);
        s += __uint_as_float(vs[q] & 0xffff0000u);
      }
    }
    float* red = (float*)lds;  // [8][33]
    red[chunk * 33 + (tid & 31)] = s;
    __syncthreads();
    if (tid < 32) {
      float tot = 0.f;
#pragma unroll
      for (int c = 0; c < 8; ++c) tot += red[c * 33 + tid];
      Xh[(size_t)b * T2 * DIN + c0 + tid] = f2bf(tot * (1.0f / 2048.0f));
    }
    return;
  }

  char* Qs = lds;
  char* Ks = lds + 16384;
  char* Vs = lds + 49152;
  float* Sf = (float*)(lds + 81920);      // [32][68]
  ushort_t* Ps = (ushort_t*)(lds + 90624);
  float* fac = (float*)(lds + 94720);     // [32]
  float* linv = fac + 32;                 // [32]
  float* Os = (float*)lds;                // epilogue reuse [32][260]

  const int ii = 63 - (int)blockIdx.x;    // heavy blocks dispatch first
  const int tq = ii >> 1;
  const int half = ii & 1;
  const int t0 = tq * 32;
  const int r0 = half ? (T_ + t0) : t0;
  const int ntop = ((t0 + 31) >> 6) + 1;
  const int dt = (T_ + t0) >> 6;
  const int nt = ntop + half;

  const int w = tid >> 6, lane = tid & 63;
  const int lr = lane & 15, kg = lane >> 4;

  // stage Q once: 32 rows x 256 d bf16, row-swizzled
#pragma unroll
  for (int s = 0; s < 4; ++s) {
    const int idx = tid + s * 256;
    const int row = idx >> 5, ch = idx & 31;
    uint4 v = *(const uint4*)&Qh[((size_t)b * T2 + r0 + row) * DD + ch * 8];
    *(uint4*)(Qs + row * 512 + ((ch * 16) ^ ((row & 7) << 4))) = v;
  }

  // softmax-thread row mapping
  const int srow = tid >> 3, sjb = tid & 7;
  float m_run = -1e30f, l_run = 0.0f;

  f32x4 acc[2][4];
  const f32x4 z4 = {0.f, 0.f, 0.f, 0.f};
#pragma unroll
  for (int a = 0; a < 2; ++a)
#pragma unroll
    for (int c = 0; c < 4; ++c) acc[a][c] = z4;

  // reg-staged K/V for current tile
  uint4 kreg[8], vreg[8];
  {
    const int kt0 = 0;
    const int ktile = (kt0 < ntop) ? kt0 : dt;
#pragma unroll
    for (int s = 0; s < 8; ++s) {
      const int idx = tid + s * 256;
      const int krow = idx >> 5, kch = idx & 31;
      kreg[s] = *(const uint4*)&Kh[((size_t)b * T2 + ktile * 64 + krow) * DD + kch * 8];
      const int vcol = idx >> 3, vch = idx & 7;
      vreg[s] = *(const uint4*)&VT[((size_t)b * DD + vcol) * T2 + ktile * 64 + vch * 8];
    }
  }

  for (int kt = 0; kt < nt; ++kt) {
    const int ktile = (kt < ntop) ? kt : dt;
    const bool isDiag = (kt >= ntop);

    __syncthreads();  // prev PV done reading Ks/Vs (first iter: Qs staged)
#pragma unroll
    for (int s = 0; s < 8; ++s) {
      const int idx = tid + s * 256;
      const int krow = idx >> 5, kch = idx & 31;
      *(uint4*)(Ks + krow * 512 + ((kch * 16) ^ ((krow & 7) << 4))) = kreg[s];
      const int vcol = idx >> 3, vch = idx & 7;
      *(uint4*)(Vs + vcol * 128 + ((vch * 16) ^ ((vcol & 7) << 4))) = vreg[s];
    }
    __syncthreads();

    if (kt + 1 < nt) {  // issue next tile's loads early (hide under compute)
      const int nktile = (kt + 1 < ntop) ? (kt + 1) : dt;
#pragma unroll
      for (int s = 0; s < 8; ++s) {
        const int idx = tid + s * 256;
        const int krow = idx >> 5, kch = idx & 31;
        kreg[s] = *(const uint4*)&Kh[((size_t)b * T2 + nktile * 64 + krow) * DD + kch * 8];
        const int vcol = idx >> 3, vch = idx & 7;
        vreg[s] = *(const uint4*)&VT[((size_t)b * DD + vcol) * T2 + nktile * 64 + vch * 8];
      }
    }

    // QK^T: wave w computes S cols w*16..w*16+15
    f32x4 accs[2];
    accs[0] = z4; accs[1] = z4;
#pragma unroll
    for (int kk = 0; kk < 8; ++kk) {
      const int cb = kk * 64 + kg * 16;
      short8 bf = *(const short8*)(Ks + (w * 16 + lr) * 512 + (cb ^ (((w * 16 + lr) & 7) << 4)));
#pragma unroll
      for (int mi = 0; mi < 2; ++mi) {
        const int row = mi * 16 + lr;
        short8 af = *(const short8*)(Qs + row * 512 + (cb ^ ((row & 7) << 4)));
        accs[mi] = __builtin_amdgcn_mfma_f32_16x16x32_bf16(af, bf, accs[mi], 0, 0, 0);
      }
    }
#pragma unroll
    for (int mi = 0; mi < 2; ++mi)
#pragma unroll
      for (int r = 0; r < 4; ++r)
        Sf[(mi * 16 + kg * 4 + r) * 68 + w * 16 + lr] = accs[mi][r];
    __syncthreads();

    // online softmax: thread (srow, sjb) handles 8 entries
    {
      const float* sp = &Sf[srow * 68 + sjb * 8];
      float sv[8];
      float tmax = -1e30f;
      const int jg0 = ktile * 64 + sjb * 8;
      const int limv = t0 + srow;
#pragma unroll
      for (int e = 0; e < 8; ++e) {
        const int jg = jg0 + e;
        const bool valid = isDiag ? (jg == T_ + limv) : (jg < limv);
        sv[e] = valid ? sp[e] * 0.0625f : -1e30f;
        tmax = fmaxf(tmax, sv[e]);
      }
#pragma unroll
      for (int off = 1; off < 8; off <<= 1) tmax = fmaxf(tmax, __shfl_xor(tmax, off, 64));
      const float m_new = fmaxf(m_run, tmax);
      const float facv = expf(m_run - m_new);
      float psum = 0.f;
      float pv[8];
#pragma unroll
      for (int e = 0; e < 8; ++e) {
        const float p = (sv[e] > -1e29f) ? expf(sv[e] - m_new) : 0.0f;
        pv[e] = p; psum += p;
      }
#pragma unroll
      for (int off = 1; off < 8; off <<= 1) psum += __shfl_xor(psum, off, 64);
      l_run = l_run * facv + psum;
      m_run = m_new;
      uint4 pk;
      pk.x = pack2(pv[0], pv[1]); pk.y = pack2(pv[2], pv[3]);
      pk.z = pack2(pv[4], pv[5]); pk.w = pack2(pv[6], pv[7]);
      *(uint4*)((char*)Ps + srow * 128 + ((sjb * 16) ^ ((srow & 7) << 4))) = pk;
      if (sjb == 0) fac[srow] = facv;
    }
    __syncthreads();

    // rescale O accumulators, then PV
#pragma unroll
    for (int mi = 0; mi < 2; ++mi) {
      float fr[4];
#pragma unroll
      for (int r = 0; r < 4; ++r) fr[r] = fac[mi * 16 + kg * 4 + r];
#pragma unroll
      for (int ni = 0; ni < 4; ++ni)
#pragma unroll
        for (int r = 0; r < 4; ++r) acc[mi][ni][r] *= fr[r];
    }
#pragma unroll
    for (int kk = 0; kk < 2; ++kk) {
      const int cb = kk * 64 + kg * 16;
      short8 af[2], bfr[4];
#pragma unroll
      for (int mi = 0; mi < 2; ++mi) {
        const int row = mi * 16 + lr;
        af[mi] = *(const short8*)((const char*)Ps + row * 128 + (cb ^ ((row & 7) << 4)));
      }
#pragma unroll
      for (int ni = 0; ni < 4; ++ni) {
        const int col = w * 64 + ni * 16 + lr;
        bfr[ni] = *(const short8*)(Vs + col * 128 + (cb ^ ((col & 7) << 4)));
      }
#pragma unroll
      for (int mi = 0; mi < 2; ++mi)
#pragma unroll
        for (int ni = 0; ni < 4; ++ni)
          acc[mi][ni] = __builtin_amdgcn_mfma_f32_16x16x32_bf16(af[mi], bfr[ni], acc[mi][ni], 0, 0, 0);
    }
  }

  // final 1/l
  if (sjb == 0) linv[srow] = 1.0f / l_run;
  __syncthreads();
#pragma unroll
  for (int mi = 0; mi < 2; ++mi) {
    float fr[4];
#pragma unroll
    for (int r = 0; r < 4; ++r) fr[r] = linv[mi * 16 + kg * 4 + r];
#pragma unroll
    for (int ni = 0; ni < 4; ++ni)
#pragma unroll
      for (int r = 0; r < 4; ++r) acc[mi][ni][r] *= fr[r];
  }
  __syncthreads();

  // transpose acc into LDS f32 [32][260]
#pragma unroll
  for (int mi = 0; mi < 2; ++mi)
#pragma unroll
    for (int ni = 0; ni < 4; ++ni) {
      const int col = w * 64 + ni * 16 + lr;
#pragma unroll
      for (int rr = 0; rr < 4; ++rr)
        Os[(mi * 16 + kg * 4 + rr) * 260 + col] = acc[mi][ni][rr];
    }
  __syncthreads();

  const int row = tid >> 3, c0 = (tid & 7) * 32;
  const int t = t0 + row;
  const float* orow = &Os[row * 260 + c0];

  if (!half) {
    if (t != 0) {  // row 0 written by the row0 blocks
      ushort_t* xp = Xh + ((size_t)b * T2 + t) * DIN + c0;
#pragma unroll
      for (int j = 0; j < 32; j += 8) {
        uint4 pk;
        pk.x = pack2(orow[j + 0], orow[j + 1]);
        pk.y = pack2(orow[j + 2], orow[j + 3]);
        pk.z = pack2(orow[j + 4], orow[j + 5]);
        pk.w = pack2(orow[j + 6], orow[j + 7]);
        *(uint4*)(xp + j) = pk;
      }
    }
  } else {
    float* cp = Cur + ((size_t)b * T_ + t) * DD + c0;
    float u[32];
    float s1 = 0.f, s2 = 0.f;
#pragma unroll
    for (int j = 0; j < 32; ++j) {
      const float x = tanhf(orow[j]) + cp[j];
      u[j] = x; s1 += x; s2 += x * x;
    }
#pragma unroll
    for (int off = 1; off < 8; off <<= 1) {
      s1 += __shfl_xor(s1, off, 64);
      s2 += __shfl_xor(s2, off, 64);
    }
    const float mean = s1 * (1.0f / 256.0f);
    const float var = s2 * (1.0f / 256.0f) - mean * mean;
    const float rinv = rsqrtf(var + LNEPS);
    ushort_t* xp = Xh + ((size_t)b * T2 + T_ + t) * DIN + c0;
    if (lastLayer) {
      float* op = out + ((size_t)b * T_ + t) * (DD * 4) + h * DD + c0;
#pragma unroll
      for (int j = 0; j < 32; ++j) {
        op[j] = (u[j] - mean) * rinv * nw[c0 + j] + nb[c0 + j];
        cp[j] = 0.0f;
      }
      const uint4 zz = {0u, 0u, 0u, 0u};
#pragma unroll
      for (int j = 0; j < 32; j += 8) *(uint4*)(xp + j) = zz;
    } else {
#pragma unroll
      for (int j = 0; j < 32; ++j) {
        const float y = (u[j] - mean) * rinv * nw[c0 + j] + nb[c0 + j];
        cp[j] = y;
        xp[j] = f2bf(y);
      }
    }
  }
}

extern "C" void kernel_launch(void* const* d_in, const int* in_sizes, int n_in,
                              void* d_out, int out_size, void* d_ws, size_t ws_size,
                              hipStream_t stream) {
  const float* ev = (const float*)d_in[0];
  const float* tm = (const float*)d_in[1];
  const float* Wt = (const float*)d_in[3];
  const float* bt = (const float*)d_in[4];
  const float* Wq = (const float*)d_in[5];
  const float* bq = (const float*)d_in[6];
  const float* Wk = (const float*)d_in[7];
  const float* bk = (const float*)d_in[8];
  const float* Wv = (const float*)d_in[9];
  const float* bv = (const float*)d_in[10];
  const float* nw = (const float*)d_in[11];
  const float* nb = (const float*)d_in[12];
  float* out = (float*)d_out;

  char* p = (char*)d_ws;
  ushort_t* Xh = (ushort_t*)p; p += (size_t)BB * T2 * DIN * 2;   // 8.39 MB
  ushort_t* Qh = (ushort_t*)p; p += (size_t)BB * T2 * DD * 2;    // 4.19 MB
  ushort_t* Kh = (ushort_t*)p; p += (size_t)BB * T2 * DD * 2;
  ushort_t* VT = (ushort_t*)p; p += (size_t)BB * T2 * DD * 2;
  float* Cur   = (float*)p;    p += (size_t)BB * T_ * DD * 4;    // 4.19 MB
  ushort_t* WT = (ushort_t*)p;                                   // 9.44 MB

  k_init<<<BB * T_, 256, 0, stream>>>(ev, tm, Wt, bt, Xh, Cur);
  k_transW<<<dim3(36, 32), 256, 0, stream>>>(Wq, Wk, Wv, WT);

  for (int h = 0; h < 4; ++h) {
    for (int l = 0; l < 3; ++l) {
      const int hl = h * 3 + l;
      const size_t boff = (size_t)hl * DD;
      k_qkv<<<dim3(64, 2, 3), 256, 0, stream>>>(Xh, WT, bq + boff, bk + boff, bv + boff,
                                                Qh, Kh, VT, hl);
      k_flash<<<dim3(72, BB), 256, 0, stream>>>(Qh, Kh, VT, Cur, Xh, out, nw, nb,
                                                (l == 2) ? 1 : 0, h);
    }
  }
}